// Round 1
// baseline (2306.143 us; speedup 1.0000x reference)
//
#include <hip/hip_runtime.h>
#include <math.h>

#define N_NODES 6144
#define KCL 20
#define NE 98304

// ---------------- workspace layout (bytes) ----------------
#define OFF_T        0ull          // 122880 f32 (zeroed)
#define OFF_BITMAP   491520ull     // 1179648 u32 (zeroed)
#define OFF_COLSUM0  5210112ull    // 20 f32 (zeroed)
#define OFF_CSG      5210192ull    // 20 f32 (zeroed)
#define OFF_CSFIN    5210272ull    // 20 f32 (zeroed)
#define OFF_FLAG     5210352ull    // int (zeroed)
#define OFF_DACC     5210368ull    // 4 doubles (zeroed): [0]=all-pair log1mp, [1]=edge term, [2]=entropy
#define ZERO_BYTES   5210400ull
#define OFF_LOGITS   5210624ull
#define OFF_S0       5702144ull
#define OFF_S1       6193664ull
#define OFF_SW       6685184ull
#define OFF_XE       7176704ull
#define OFF_G        13468160ull
#define OFF_TROW     13492736ull

// ---------------- MLP: logits = (relu(relu(x@W1+b1)@W2+b2))@W3+b3 ----------------
__global__ __launch_bounds__(128) void k_mlp(const float* __restrict__ x,
    const float* __restrict__ W1, const float* __restrict__ b1,
    const float* __restrict__ W2, const float* __restrict__ b2,
    const float* __restrict__ W3, const float* __restrict__ b3,
    float* __restrict__ logits){
  __shared__ float xs[16][256];
  __shared__ float h1[16][128];
  __shared__ float h2[16][64];
  const int tid = threadIdx.x;
  const int r0 = blockIdx.x * 16;
  for (int idx = tid; idx < 16*256; idx += 128){ int u = idx >> 8, i = idx & 255; xs[u][i] = x[(r0+u)*256 + i]; }
  __syncthreads();
  {
    float acc[16]; float bb = b1[tid];
    #pragma unroll
    for (int u=0;u<16;u++) acc[u]=bb;
    for (int i=0;i<256;i++){ float wv = W1[i*128+tid];
      #pragma unroll
      for (int u=0;u<16;u++) acc[u]=fmaf(xs[u][i], wv, acc[u]); }
    #pragma unroll
    for (int u=0;u<16;u++) h1[u][tid]=fmaxf(acc[u],0.f);
  }
  __syncthreads();
  if (tid < 64){
    float acc[16]; float bb = b2[tid];
    #pragma unroll
    for (int u=0;u<16;u++) acc[u]=bb;
    for (int i=0;i<128;i++){ float wv = W2[i*64+tid];
      #pragma unroll
      for (int u=0;u<16;u++) acc[u]=fmaf(h1[u][i], wv, acc[u]); }
    #pragma unroll
    for (int u=0;u<16;u++) h2[u][tid]=fmaxf(acc[u],0.f);
  }
  __syncthreads();
  if (tid < 20){
    float acc[16]; float bb = b3[tid];
    #pragma unroll
    for (int u=0;u<16;u++) acc[u]=bb;
    for (int i=0;i<64;i++){ float wv = W3[i*20+tid];
      #pragma unroll
      for (int u=0;u<16;u++) acc[u]=fmaf(h2[u][i], wv, acc[u]); }
    #pragma unroll
    for (int u=0;u<16;u++) logits[(r0+u)*20+tid]=acc[u];
  }
}

// ---------------- embed MLP: xe = relu(x@We1+be1)@We2+be2 ----------------
__global__ __launch_bounds__(256) void k_embed(const float* __restrict__ x,
    const float* __restrict__ We1, const float* __restrict__ be1,
    const float* __restrict__ We2, const float* __restrict__ be2,
    float* __restrict__ xe){
  __shared__ float xs[16][256];
  __shared__ float h[16][256];
  const int tid = threadIdx.x;
  const int r0 = blockIdx.x * 16;
  for (int u=0;u<16;u++) xs[u][tid] = x[(r0+u)*256 + tid];
  __syncthreads();
  float acc[16];
  { float bb = be1[tid];
    #pragma unroll
    for (int u=0;u<16;u++) acc[u]=bb; }
  for (int i=0;i<256;i++){ float wv = We1[i*256+tid];
    #pragma unroll
    for (int u=0;u<16;u++) acc[u]=fmaf(xs[u][i], wv, acc[u]); }
  #pragma unroll
  for (int u=0;u<16;u++) h[u][tid]=fmaxf(acc[u],0.f);
  __syncthreads();
  { float bb = be2[tid];
    #pragma unroll
    for (int u=0;u<16;u++) acc[u]=bb; }
  for (int i=0;i<256;i++){ float wv = We2[i*256+tid];
    #pragma unroll
    for (int u=0;u<16;u++) acc[u]=fmaf(h[u][i], wv, acc[u]); }
  #pragma unroll
  for (int u=0;u<16;u++) xe[(r0+u)*256+tid]=acc[u];
}

// ---------------- softmax #1: colsum0 = softmax(logits).sum(axis=0) ----------------
__global__ __launch_bounds__(256) void k_sm1(const float* __restrict__ logits, float* __restrict__ colsum0){
  __shared__ float csL[20];
  const int tid = threadIdx.x;
  if (tid < 20) csL[tid]=0.f;
  __syncthreads();
  const int r = blockIdx.x*256 + tid;
  float y[20]; float m = -INFINITY;
  #pragma unroll
  for (int c=0;c<20;c++){ y[c]=logits[r*20+c]; m=fmaxf(m,y[c]); }
  float s=0.f;
  #pragma unroll
  for (int c=0;c<20;c++){ y[c]=expf(y[c]-m); s+=y[c]; }
  #pragma unroll
  for (int c=0;c<20;c++) atomicAdd(&csL[c], y[c]/s);
  __syncthreads();
  if (tid < 20) atomicAdd(&colsum0[tid], csL[tid]);
}

// ---------------- softmax #2: S0 = softmax(logits - 0.1*(colsum0-T)/T), csG = S0.sum(0) ----------------
__global__ __launch_bounds__(256) void k_sm2(const float* __restrict__ logits, const float* __restrict__ colsum0,
    float* __restrict__ S0, float* __restrict__ csG){
  __shared__ float adjv[20]; __shared__ float csL[20];
  const int tid = threadIdx.x;
  if (tid < 20){ adjv[tid] = (0.1f*(colsum0[tid]-307.2f))/307.2f; csL[tid]=0.f; }
  __syncthreads();
  const int r = blockIdx.x*256 + tid;
  float y[20]; float m=-INFINITY;
  #pragma unroll
  for (int c=0;c<20;c++){ y[c]=logits[r*20+c]-adjv[c]; m=fmaxf(m,y[c]); }
  float s=0.f;
  #pragma unroll
  for (int c=0;c<20;c++){ y[c]=expf(y[c]-m); s+=y[c]; }
  #pragma unroll
  for (int c=0;c<20;c++){ float v=y[c]/s; S0[r*20+c]=v; atomicAdd(&csL[c], v); }
  __syncthreads();
  if (tid < 20) atomicAdd(&csG[tid], csL[tid]);
}

// ---------------- prep constraints: pen, anyPen, S1 = softmax(log(S0+1e-8)+pen), g=1, trow ----------------
__global__ __launch_bounds__(256) void k_prep(const float* __restrict__ S0, const float* __restrict__ csG,
    float* __restrict__ S1, float* __restrict__ g, float* __restrict__ trow, int* __restrict__ flag){
  __shared__ float pen[20];
  const int tid = threadIdx.x;
  if (tid < 20){ float c=csG[tid]; float p=0.f;
    if (c > 20.0f) p = -logf(c/20.0f + 1e-8f);
    if (c > 0.0f && c < 3.0f) p = -0.5f*logf(c/3.0f + 1e-8f);
    pen[tid]=p; }
  __syncthreads();
  if (blockIdx.x==0 && tid==0){ int f=0; for (int c=0;c<20;c++) if (pen[c]!=0.f) f=1; if (f) *flag=1; }
  const int r = blockIdx.x*256 + tid;
  float y[20]; float m=-INFINITY;
  #pragma unroll
  for (int c=0;c<20;c++){ y[c]=logf(S0[r*20+c]+1e-8f)+pen[c]; m=fmaxf(m,y[c]); }
  float s=0.f;
  #pragma unroll
  for (int c=0;c<20;c++){ y[c]=expf(y[c]-m); s+=y[c]; }
  float ts=0.f;
  #pragma unroll
  for (int c=0;c<20;c++){ float v=y[c]/s; S1[r*20+c]=v; ts+=v; }
  trow[r]=ts; g[r]=1.0f;
}

// ---------------- block radix select (k-th smallest, non-negative f32) ----------------
// st[0]=prefix bits, st[1]=count strictly below value, st[2]=rank within equal group, st[3]=count at value
__device__ float selectKth(const float* vcol, int rank0, unsigned int* hist, unsigned int* st, int tid){
  if (tid==0){ st[0]=0u; st[1]=0u; st[2]=(unsigned)rank0; st[3]=0u; }
  __syncthreads();
  for (int p=0;p<3;p++){
    const int shift = (p==0)?21:((p==1)?10:0);
    const int bins  = (p==2)?1024:2048;
    for (int b=tid;b<bins;b+=1024) hist[b]=0u;
    __syncthreads();
    const unsigned pref = st[0];
    for (int u=0;u<6;u++){
      unsigned key = __float_as_uint(vcol[tid*6+u]);
      bool ok;
      if (p==0) ok = true;
      else { int us = (p==1)?21:10; ok = ((key>>us)==(pref>>us)); }
      if (ok) atomicAdd(&hist[(key>>shift)&(bins-1)], 1u);
    }
    __syncthreads();
    if (tid < 64){
      const int per = bins >> 6;
      const int rank = (int)st[2];
      int cnt = 0;
      for (int b=0;b<per;b++) cnt += (int)hist[tid*per+b];
      int cum = cnt;
      for (int off=1;off<64;off<<=1){ int nv=__shfl_up(cum,off); if (tid>=off) cum+=nv; }
      unsigned long long bal = __ballot(cum > rank);
      int ldr = (int)__ffsll(bal) - 1;
      int base = __shfl(cum-cnt, ldr);
      if (tid == ldr){
        int run = base; int bsel = -1; unsigned hc = 0u;
        for (int b=0;b<per;b++){ unsigned h=hist[ldr*per+b]; if (run+(int)h > rank){ bsel=ldr*per+b; hc=h; break; } run+=(int)h; }
        st[0] = st[0] | (((unsigned)bsel) << shift);
        st[1] = st[1] + (unsigned)run;
        st[2] = (unsigned)(rank - run);
        st[3] = hc;
      }
    }
    __syncthreads();
  }
  return __uint_as_float(st[0]);
}

// ---------------- constraints: sequential 20-column quantile/zero/renorm (scale-factor form) ----------------
__global__ __launch_bounds__(1024) void k_constraints(float* __restrict__ S1, float* __restrict__ g,
    float* __restrict__ trow, const float* __restrict__ csG){
  __shared__ float vcol[6144];
  __shared__ unsigned int hist[2048];
  __shared__ unsigned int st[8];
  const int tid = threadIdx.x;
  for (int k=0;k<20;k++){
    float csk = csG[k];
    if (!(csk > 30.0f)) continue;   // very_over false -> column untouched
    for (int u=0;u<6;u++){ int r=tid*6+u; vcol[r] = __fmul_rn(S1[r*20+k], g[r]); }
    __syncthreads();
    float vlo = selectKth(vcol, 4300, hist, st, tid);
    float vhi;
    if (st[2] + 1u < st[3]) vhi = vlo;   // rank 4301 within same-value run
    else {
      if (tid==0) st[4]=0xFFFFFFFFu;
      __syncthreads();
      unsigned kV = __float_as_uint(vlo);
      for (int u=0;u<6;u++){ unsigned key=__float_as_uint(vcol[tid*6+u]); if (key>kV) atomicMin(&st[4], key); }
      __syncthreads();
      vhi = __uint_as_float(st[4]);
    }
    // jnp.quantile(col,0.7): aq=f32(0.7)*6143=4300.10009765625 -> weights exact
    float thr = __fadd_rn(__fmul_rn(vlo, 0.89990234375f), __fmul_rn(vhi, 0.10009765625f));
    for (int u=0;u<6;u++){
      int r=tid*6+u; float v=vcol[r];
      if (v < thr){
        S1[r*20+k] = 0.0f;
        float rs  = __fsub_rn(trow[r], v);
        float rsm = fmaxf(rs, 1e-12f);
        g[r]    = __fdiv_rn(g[r], rsm);
        trow[r] = __fdiv_rn(rs, rsm);
      }
    }
    __syncthreads();
  }
}

// ---------------- materialize: SW = anyPen ? S1*g : S0 ----------------
__global__ __launch_bounds__(256) void k_mat(const float* __restrict__ S1, const float* __restrict__ S0,
    const float* __restrict__ g, const int* __restrict__ flag, float* __restrict__ SW){
  const int r = blockIdx.x*256 + threadIdx.x;
  const int f = *flag; const float gg = g[r];
  #pragma unroll
  for (int c=0;c<20;c++) SW[r*20+c] = f ? __fmul_rn(S1[r*20+c], gg) : S0[r*20+c];
}

// ---------------- rebalance helpers ----------------
__device__ int blockExclScan(int val, int tid, int* waveTot, int* waveBase, int* totAll){
  const int lane = tid & 63, wv = tid >> 6;
  int inc = val;
  for (int off=1;off<64;off<<=1){ int nv=__shfl_up(inc,off); if (lane>=off) inc+=nv; }
  if (lane==63) waveTot[wv]=inc;
  __syncthreads();
  if (tid==0){ int run=0; for (int w2=0;w2<16;w2++){ waveBase[w2]=run; run+=waveTot[w2]; } *totAll=run; }
  __syncthreads();
  return waveBase[wv] + inc - val;
}

__device__ __forceinline__ void updateRow(float* SW, int r, int k, const float* wL){
  float x[20]; float rs=0.f;
  #pragma unroll
  for (int j=0;j<20;j++){
    float xv = (j==k) ? 1e-8f : SW[r*20+j];
    xv = __fadd_rn(xv, __fmul_rn(wL[j], 1e-8f));
    x[j]=xv; rs += fabsf(xv);
  }
  float rsm = fmaxf(rs, 1e-12f);
  #pragma unroll
  for (int j=0;j<20;j++) SW[r*20+j] = __fdiv_rn(x[j], rsm);
}

// ---------------- hard rebalance: 5 x 20 sequential stable-rank column steps ----------------
__global__ __launch_bounds__(1024) void k_rebalance(float* __restrict__ SW){
  __shared__ float vcol[6144];
  __shared__ unsigned int hist[2048];
  __shared__ unsigned int st[8];
  __shared__ float wL[20]; __shared__ int numL[20]; __shared__ int actL[20];
  __shared__ int waveTot[16]; __shared__ int waveBase[16]; __shared__ int totAll;
  __shared__ double wred[320];
  __shared__ float csS[20]; __shared__ float wsumS;
  const int tid = threadIdx.x;
  const int lane = tid & 63, wv = tid >> 6;
  for (int it=0; it<5; it++){
    // cs = SW.sum(axis=0), f64 accumulate
    double acc[20];
    #pragma unroll
    for (int c=0;c<20;c++) acc[c]=0.0;
    for (int u=0;u<6;u++){ int r=tid*6+u;
      #pragma unroll
      for (int c=0;c<20;c++) acc[c] += (double)SW[r*20+c]; }
    #pragma unroll
    for (int c=0;c<20;c++){
      double d = acc[c];
      for (int off=32;off>0;off>>=1) d += __shfl_down(d, off);
      if (lane==0) wred[wv*20+c]=d;
    }
    __syncthreads();
    if (tid < 20){ double s=0.0; for (int w2=0;w2<16;w2++) s += wred[w2*20+tid]; csS[tid]=(float)s; }
    __syncthreads();
    if (tid==0){ float s=0.f; for (int c=0;c<20;c++) s += fmaxf(20.0f-csS[c],0.f); wsumS = s + 1e-8f; }
    __syncthreads();
    if (tid < 20){
      float csf = csS[tid];
      actL[tid] = (csf > 20.0f) ? 1 : 0;
      int num = (int)ceilf(csf - 20.0f) + 5; if (num > 6144) num = 6144;
      numL[tid] = num;
      wL[tid] = fmaxf(20.0f-csf,0.f) / wsumS;
    }
    __syncthreads();
    for (int k=0;k<20;k++){
      if (!actL[k]) continue;
      const int num = numL[k];
      float v[6]; int zc=0;
      #pragma unroll
      for (int u=0;u<6;u++){ v[u]=SW[(tid*6+u)*20+k]; zc += (v[u]==0.0f) ? 1 : 0; }
      int zBase = blockExclScan(zc, tid, waveTot, waveBase, &totAll);
      if (num <= totAll){
        // fast path: cutoff value is exactly 0; weak = first `num` zero rows by index (stable ties)
        int cnt = zBase;
        #pragma unroll
        for (int u=0;u<6;u++){
          if (v[u]==0.0f){ if (cnt < num) updateRow(SW, tid*6+u, k, wL); cnt++; }
        }
      } else {
        #pragma unroll
        for (int u=0;u<6;u++) vcol[tid*6+u]=v[u];
        __syncthreads();
        float V = selectKth(vcol, num-1, hist, st, tid);
        unsigned kV = __float_as_uint(V);
        int L = (int)st[1];
        int R = num - L;
        int ec=0;
        #pragma unroll
        for (int u=0;u<6;u++) ec += (__float_as_uint(v[u])==kV) ? 1 : 0;
        int eBase = blockExclScan(ec, tid, waveTot, waveBase, &totAll);
        int cnt = eBase;
        #pragma unroll
        for (int u=0;u<6;u++){
          unsigned key = __float_as_uint(v[u]);
          if (key < kV) updateRow(SW, tid*6+u, k, wL);
          else if (key == kV){ if (cnt < R) updateRow(SW, tid*6+u, k, wL); cnt++; }
        }
      }
      __syncthreads();
    }
  }
}

// ---------------- final pass: store S, entropy, cs_final, x_pooled ----------------
__global__ __launch_bounds__(256) void k_final(const float* __restrict__ SW, const float* __restrict__ xe,
    float* __restrict__ outXP, float* __restrict__ outS, float* __restrict__ csfin, double* __restrict__ entAcc){
  __shared__ float srow[8][20];
  __shared__ float csL[20];
  __shared__ double entL[4];
  const int tid = threadIdx.x;
  const int r0 = blockIdx.x * 256;
  const int lane = tid & 63, wvq = tid >> 6;
  if (tid < 20) csL[tid]=0.f;
  __syncthreads();
  // phase A
  {
    const int r = r0 + tid;
    float sv[20]; float ent=0.f;
    #pragma unroll
    for (int c=0;c<20;c++){ sv[c]=SW[r*20+c]; }
    #pragma unroll
    for (int c=0;c<20;c++){ outS[r*20+c]=sv[c]; ent += sv[c]*logf(sv[c]+1e-8f); }
    #pragma unroll
    for (int c=0;c<20;c++) atomicAdd(&csL[c], sv[c]);
    double ed = (double)ent;
    for (int off=32;off>0;off>>=1) ed += __shfl_down(ed, off);
    if (lane==0) entL[wvq]=ed;
  }
  __syncthreads();
  if (tid==0) atomicAdd(entAcc, entL[0]+entL[1]+entL[2]+entL[3]);
  if (tid<20) atomicAdd(&csfin[tid], csL[tid]);
  __syncthreads();
  // phase B: x_pooled partial (thread owns output feature tid)
  float acc[20];
  #pragma unroll
  for (int c=0;c<20;c++) acc[c]=0.f;
  for (int base=0;base<256;base+=8){
    if (tid < 160){ int i=tid/20, c=tid%20; srow[i][c]=SW[(r0+base+i)*20+c]; }
    __syncthreads();
    for (int i=0;i<8;i++){
      float xv = xe[(r0+base+i)*256 + tid];
      #pragma unroll
      for (int c=0;c<20;c++) acc[c]=fmaf(srow[i][c], xv, acc[c]);
    }
    __syncthreads();
  }
  #pragma unroll
  for (int c=0;c<20;c++) atomicAdd(&outXP[c*256+tid], acc[c]);
}

// ---------------- edges: dedup bitmap, T = adj@S, edge loss term ----------------
__global__ __launch_bounds__(256) void k_edges(const int* __restrict__ ei, const float* __restrict__ SW,
    unsigned int* __restrict__ bitmap, float* __restrict__ T, double* __restrict__ edgeAcc){
  __shared__ double wsum[4];
  const int tid = threadIdx.x;
  const int e = blockIdx.x*256 + tid;
  const int lane = tid & 63, wvq = tid >> 6;
  const int i = ei[e], j = ei[NE+e];
  unsigned bit = (unsigned)i*6144u + (unsigned)j;
  unsigned w = bit >> 5, m = 1u << (bit & 31u);
  unsigned old = atomicOr(&bitmap[w], m);
  float contrib = 0.f;
  if (!(old & m)){
    float p = 0.f;
    #pragma unroll
    for (int c=0;c<20;c++) p = fmaf(SW[i*20+c], SW[j*20+c], p);
    #pragma unroll
    for (int c=0;c<20;c++) atomicAdd(&T[i*20+c], SW[j*20+c]);
    float pcl = fminf(fmaxf(p,0.f),1.f);
    float lg  = fmaxf(logf(pcl),   -100.f);
    float l1  = fmaxf(log1pf(-pcl),-100.f);
    contrib = lg - l1;
  }
  double cd = (double)contrib;
  for (int off=32;off>0;off>>=1) cd += __shfl_down(cd, off);
  if (lane==0) wsum[wvq]=cd;
  __syncthreads();
  if (tid==0) atomicAdd(edgeAcc, wsum[0]+wsum[1]+wsum[2]+wsum[3]);
}

// ---------------- adj_pooled = S.T @ T ----------------
__global__ __launch_bounds__(400) void k_adjpool(const float* __restrict__ SW, const float* __restrict__ T,
    float* __restrict__ outAdj){
  const int tid = threadIdx.x;          // 0..399
  const int c = tid/20, d = tid%20;
  const int r0 = blockIdx.x*256;
  float acc=0.f;
  for (int i=0;i<256;i++) acc = fmaf(SW[(r0+i)*20+c], T[(r0+i)*20+d], acc);
  atomicAdd(&outAdj[c*20+d], acc);
}

// ---------------- all-pair sum of clamped log1p(-p) ----------------
__global__ __launch_bounds__(256) void k_link(const float* __restrict__ SW, double* __restrict__ acc){
  __shared__ float Si[256][21];
  __shared__ float Sj[256][21];
  __shared__ double wsum[4];
  const int tid = threadIdx.x;
  const int ib = blockIdx.x*256, jb = blockIdx.y*256;
  const int lane = tid & 63, wvq = tid >> 6;
  for (int idx=tid; idx<5120; idx+=256){ int r=idx/20, c=idx%20; Si[r][c]=SW[(ib+r)*20+c]; }
  for (int idx=tid; idx<5120; idx+=256){ int r=idx/20, c=idx%20; Sj[r][c]=SW[(jb+r)*20+c]; }
  __syncthreads();
  float rA[20];
  #pragma unroll
  for (int c=0;c<20;c++) rA[c]=Si[tid][c];
  float af = 0.f;
  for (int jj=0;jj<256;jj++){
    float p=0.f;
    #pragma unroll
    for (int c=0;c<20;c++) p = fmaf(rA[c], Sj[jj][c], p);
    float pcl = fminf(fmaxf(p,0.f),1.f);
    af += fmaxf(log1pf(-pcl), -100.f);
  }
  double cd = (double)af;
  for (int off=32;off>0;off>>=1) cd += __shfl_down(cd, off);
  if (lane==0) wsum[wvq]=cd;
  __syncthreads();
  if (tid==0) atomicAdd(acc, wsum[0]+wsum[1]+wsum[2]+wsum[3]);
}

// ---------------- aux scalar ----------------
__global__ void k_aux(const double* __restrict__ dAcc, const float* __restrict__ csfin, float* __restrict__ outAux){
  const double nsq = 6144.0*6144.0;
  float link = (float)(-(dAcc[0]+dAcc[1])/nsq);
  float ent  = (float)(-(dAcc[2]/6144.0));
  float s=0.f;
  for (int c=0;c<20;c++) s += fabsf(csfin[c]-307.2f);
  float bal = (s/20.0f)/307.2f;
  outAux[0] = link + 0.1f*ent + 0.5f*bal;
}

extern "C" void kernel_launch(void* const* d_in, const int* in_sizes, int n_in,
                              void* d_out, int out_size, void* d_ws, size_t ws_size,
                              hipStream_t stream) {
  const float* x   = (const float*)d_in[0];
  const int*   ei  = (const int*)d_in[1];
  // d_in[2] = lv_group_ids: dead (LV table is never 0 -> mask is identity)
  const float* W1  = (const float*)d_in[3];
  const float* b1  = (const float*)d_in[4];
  const float* W2  = (const float*)d_in[5];
  const float* b2  = (const float*)d_in[6];
  const float* W3  = (const float*)d_in[7];
  const float* b3  = (const float*)d_in[8];
  const float* We1 = (const float*)d_in[9];
  const float* be1 = (const float*)d_in[10];
  const float* We2 = (const float*)d_in[11];
  const float* be2 = (const float*)d_in[12];

  char* ws = (char*)d_ws;
  float* T        = (float*)(ws + OFF_T);
  unsigned int* bitmap = (unsigned int*)(ws + OFF_BITMAP);
  float* colsum0  = (float*)(ws + OFF_COLSUM0);
  float* csG      = (float*)(ws + OFF_CSG);
  float* csfin    = (float*)(ws + OFF_CSFIN);
  int*   flag     = (int*)(ws + OFF_FLAG);
  double* dAcc    = (double*)(ws + OFF_DACC);
  float* logits   = (float*)(ws + OFF_LOGITS);
  float* S0       = (float*)(ws + OFF_S0);
  float* S1       = (float*)(ws + OFF_S1);
  float* SW       = (float*)(ws + OFF_SW);
  float* xe       = (float*)(ws + OFF_XE);
  float* g        = (float*)(ws + OFF_G);
  float* trow     = (float*)(ws + OFF_TROW);

  float* out   = (float*)d_out;
  float* outXP = out;            // 20*256
  float* outAdj= out + 5120;     // 20*20
  float* outS  = out + 5520;     // 6144*20
  float* outAux= out + 128400;   // 1

  hipMemsetAsync(d_ws, 0, (size_t)ZERO_BYTES, stream);
  hipMemsetAsync(d_out, 0, (size_t)out_size*sizeof(float), stream);

  k_mlp<<<384, 128, 0, stream>>>(x, W1,b1, W2,b2, W3,b3, logits);
  k_embed<<<384, 256, 0, stream>>>(x, We1,be1, We2,be2, xe);
  k_sm1<<<24, 256, 0, stream>>>(logits, colsum0);
  k_sm2<<<24, 256, 0, stream>>>(logits, colsum0, S0, csG);
  k_prep<<<24, 256, 0, stream>>>(S0, csG, S1, g, trow, flag);
  k_constraints<<<1, 1024, 0, stream>>>(S1, g, trow, csG);
  k_mat<<<24, 256, 0, stream>>>(S1, S0, g, flag, SW);
  k_rebalance<<<1, 1024, 0, stream>>>(SW);
  k_final<<<24, 256, 0, stream>>>(SW, xe, outXP, outS, csfin, &dAcc[2]);
  k_edges<<<384, 256, 0, stream>>>(ei, SW, bitmap, T, &dAcc[1]);
  k_adjpool<<<24, 400, 0, stream>>>(SW, T, outAdj);
  k_link<<<dim3(24,24), 256, 0, stream>>>(SW, &dAcc[0]);
  k_aux<<<1, 1, 0, stream>>>(dAcc, csfin, outAux);
}

// Round 2
// 1957.818 us; speedup vs baseline: 1.1779x; 1.1779x over previous
//
#include <hip/hip_runtime.h>
#include <math.h>

#define N_NODES 6144
#define KCL 20
#define NE 98304

// ---------------- workspace layout (bytes) ----------------
#define OFF_T        0ull          // 122880 f32 (zeroed)
#define OFF_BITMAP   491520ull     // 4718592 B bitmap (zeroed)
#define OFF_COLSUM0  5210112ull    // (unused, kept for layout)
#define OFF_CSG      5210192ull    // (unused)
#define OFF_CSFIN    5210272ull    // 20 f32 (zeroed)
#define OFF_FLAG     5210352ull    // (unused)
#define OFF_DACC     5210368ull    // 4 doubles (zeroed): [0]=all-pair log1mp, [1]=edge term, [2]=entropy
#define ZERO_BYTES   5210400ull
#define OFF_LOGITS   5210624ull
#define OFF_UCM      5702144ull    // 6144*20 f32 column-major  (was S0)
#define OFF_SW       6685184ull    // 6144*20 f32 row-major
#define OFF_XE       7176704ull    // 6144*256 f32

// ---------------- MLP: logits = (relu(relu(x@W1+b1)@W2+b2))@W3+b3 ----------------
__global__ __launch_bounds__(128) void k_mlp(const float* __restrict__ x,
    const float* __restrict__ W1, const float* __restrict__ b1,
    const float* __restrict__ W2, const float* __restrict__ b2,
    const float* __restrict__ W3, const float* __restrict__ b3,
    float* __restrict__ logits){
  __shared__ float xs[16][256];
  __shared__ float h1[16][128];
  __shared__ float h2[16][64];
  const int tid = threadIdx.x;
  const int r0 = blockIdx.x * 16;
  for (int idx = tid; idx < 16*256; idx += 128){ int u = idx >> 8, i = idx & 255; xs[u][i] = x[(r0+u)*256 + i]; }
  __syncthreads();
  {
    float acc[16]; float bb = b1[tid];
    #pragma unroll
    for (int u=0;u<16;u++) acc[u]=bb;
    for (int i=0;i<256;i++){ float wv = W1[i*128+tid];
      #pragma unroll
      for (int u=0;u<16;u++) acc[u]=fmaf(xs[u][i], wv, acc[u]); }
    #pragma unroll
    for (int u=0;u<16;u++) h1[u][tid]=fmaxf(acc[u],0.f);
  }
  __syncthreads();
  if (tid < 64){
    float acc[16]; float bb = b2[tid];
    #pragma unroll
    for (int u=0;u<16;u++) acc[u]=bb;
    for (int i=0;i<128;i++){ float wv = W2[i*64+tid];
      #pragma unroll
      for (int u=0;u<16;u++) acc[u]=fmaf(h1[u][i], wv, acc[u]); }
    #pragma unroll
    for (int u=0;u<16;u++) h2[u][tid]=fmaxf(acc[u],0.f);
  }
  __syncthreads();
  if (tid < 20){
    float acc[16]; float bb = b3[tid];
    #pragma unroll
    for (int u=0;u<16;u++) acc[u]=bb;
    for (int i=0;i<64;i++){ float wv = W3[i*20+tid];
      #pragma unroll
      for (int u=0;u<16;u++) acc[u]=fmaf(h2[u][i], wv, acc[u]); }
    #pragma unroll
    for (int u=0;u<16;u++) logits[(r0+u)*20+tid]=acc[u];
  }
}

// ---------------- embed MLP: xe = relu(x@We1+be1)@We2+be2 ----------------
__global__ __launch_bounds__(256) void k_embed(const float* __restrict__ x,
    const float* __restrict__ We1, const float* __restrict__ be1,
    const float* __restrict__ We2, const float* __restrict__ be2,
    float* __restrict__ xe){
  __shared__ float xs[16][256];
  __shared__ float h[16][256];
  const int tid = threadIdx.x;
  const int r0 = blockIdx.x * 16;
  for (int u=0;u<16;u++) xs[u][tid] = x[(r0+u)*256 + tid];
  __syncthreads();
  float acc[16];
  { float bb = be1[tid];
    #pragma unroll
    for (int u=0;u<16;u++) acc[u]=bb; }
  for (int i=0;i<256;i++){ float wv = We1[i*256+tid];
    #pragma unroll
    for (int u=0;u<16;u++) acc[u]=fmaf(xs[u][i], wv, acc[u]); }
  #pragma unroll
  for (int u=0;u<16;u++) h[u][tid]=fmaxf(acc[u],0.f);
  __syncthreads();
  { float bb = be2[tid];
    #pragma unroll
    for (int u=0;u<16;u++) acc[u]=bb; }
  for (int i=0;i<256;i++){ float wv = We2[i*256+tid];
    #pragma unroll
    for (int u=0;u<16;u++) acc[u]=fmaf(h[u][i], wv, acc[u]); }
  #pragma unroll
  for (int u=0;u<16;u++) xe[(r0+u)*256+tid]=acc[u];
}

// ---------------- helpers for the fused middle kernel ----------------
__device__ __forceinline__ void reduce20(const double* acc, double* wred, float* out,
                                         int tid, int lane, int wv){
  #pragma unroll
  for (int c=0;c<20;c++){
    double d = acc[c];
    for (int off=32;off>0;off>>=1) d += __shfl_down(d, off);
    if (lane==0) wred[wv*20+c]=d;
  }
  __syncthreads();
  if (tid<20){ double s=0.0; for (int w2=0;w2<16;w2++) s += wred[w2*20+tid]; out[tid]=(float)s; }
  __syncthreads();
}

__device__ int blockExclScan(int val, int tid, int* waveTot, int* waveBase, int* totAll){
  __syncthreads();   // protect reuse of waveTot/totAll across back-to-back calls
  const int lane = tid & 63, wv = tid >> 6;
  int inc = val;
  for (int off=1;off<64;off<<=1){ int nv=__shfl_up(inc,off); if (lane>=off) inc+=nv; }
  if (lane==63) waveTot[wv]=inc;
  __syncthreads();
  if (tid==0){ int run=0; for (int w2=0;w2<16;w2++){ waveBase[w2]=run; run+=waveTot[w2]; } *totAll=run; }
  __syncthreads();
  return waveBase[wv] + inc - val;
}

// block radix select (k-th smallest, non-negative f32), 4-replica histogram
// st[0]=prefix bits, st[1]=count strictly below value, st[2]=rank within equal group, st[3]=count at value
__device__ float selectKth6(const float v6[6], int rank0, unsigned int (*hist)[2048],
                            unsigned int* st, int tid){
  const int rep = (tid>>6)&3;
  if (tid==0){ st[0]=0u; st[1]=0u; st[2]=(unsigned)rank0; st[3]=0u; }
  __syncthreads();
  for (int p=0;p<3;p++){
    const int shift = (p==0)?21:((p==1)?10:0);
    const int bins  = (p==2)?1024:2048;
    for (int b=tid;b<bins;b+=1024){ hist[0][b]=0u; hist[1][b]=0u; hist[2][b]=0u; hist[3][b]=0u; }
    __syncthreads();
    const unsigned pref = st[0];
    #pragma unroll
    for (int u=0;u<6;u++){
      unsigned key = __float_as_uint(v6[u]);
      bool ok;
      if (p==0) ok = true;
      else { int us = (p==1)?21:10; ok = ((key>>us)==(pref>>us)); }
      if (ok) atomicAdd(&hist[rep][(key>>shift)&(bins-1)], 1u);
    }
    __syncthreads();
    if (tid < 64){
      const int per = bins >> 6;
      const int rank = (int)st[2];
      int cnt = 0;
      for (int b=0;b<per;b++){ int i=tid*per+b; cnt += (int)(hist[0][i]+hist[1][i]+hist[2][i]+hist[3][i]); }
      int cum = cnt;
      for (int off=1;off<64;off<<=1){ int nv=__shfl_up(cum,off); if (tid>=off) cum+=nv; }
      unsigned long long bal = __ballot(cum > rank);
      int ldr = (int)__ffsll(bal) - 1;
      int base = __shfl(cum-cnt, ldr);
      if (tid == ldr){
        int run = base; int bsel = -1; unsigned hc = 0u;
        for (int b=0;b<per;b++){ int i=ldr*per+b;
          unsigned h = hist[0][i]+hist[1][i]+hist[2][i]+hist[3][i];
          if (run+(int)h > rank){ bsel=i; hc=h; break; } run+=(int)h; }
        st[0] = st[0] | (((unsigned)bsel) << shift);
        st[1] = st[1] + (unsigned)run;
        st[2] = (unsigned)(rank - run);
        st[3] = hc;
      }
    }
    __syncthreads();
  }
  return __uint_as_float(st[0]);
}

// ---------------- fused middle: sm1+sm2+prep+constraints+mat+rebalance ----------------
// Rows r = tid*6+u are thread-private; S kept as Ucm (column-major, unscaled) plus
// per-row scale G6 and unscaled row-sum R6 in registers. Row rescales are O(1).
__global__ __launch_bounds__(1024) void k_mid(const float* __restrict__ logits,
    float* __restrict__ Ucm, float* __restrict__ SW){
  __shared__ unsigned int hist[4][2048];
  __shared__ unsigned int st[8];
  __shared__ int waveTot[16]; __shared__ int waveBase[16]; __shared__ int totAllS;
  __shared__ double wred[320];
  __shared__ float cs0s[20], csGs[20], adjS[20], pen[20], csS[20], wLs[20];
  __shared__ int numL[20], actL[20];
  __shared__ float wsumS; __shared__ int wzeroS; __shared__ int flagS;
  const int tid = threadIdx.x;
  const int lane = tid & 63, wv = tid >> 6;
  const int r0 = tid*6;

  double acc[20];
  // ---- pass 1: colsum0 = softmax(logits).sum(0) ----
  #pragma unroll
  for (int c=0;c<20;c++) acc[c]=0.0;
  for (int u=0;u<6;u++){
    const int r = r0+u;
    float y[20];
    const float4* lp = (const float4*)(logits + r*20);
    #pragma unroll
    for (int q=0;q<5;q++){ float4 f=lp[q]; y[q*4]=f.x; y[q*4+1]=f.y; y[q*4+2]=f.z; y[q*4+3]=f.w; }
    float m=-INFINITY;
    #pragma unroll
    for (int c=0;c<20;c++) m=fmaxf(m,y[c]);
    float s=0.f;
    #pragma unroll
    for (int c=0;c<20;c++){ y[c]=expf(y[c]-m); s+=y[c]; }
    #pragma unroll
    for (int c=0;c<20;c++) acc[c] += (double)(y[c]/s);
  }
  reduce20(acc, wred, cs0s, tid, lane, wv);
  if (tid<20) adjS[tid] = (0.1f*(cs0s[tid]-307.2f))/307.2f;
  __syncthreads();

  // ---- pass 2: csG = softmax(logits-adj).sum(0) ----
  #pragma unroll
  for (int c=0;c<20;c++) acc[c]=0.0;
  for (int u=0;u<6;u++){
    const int r = r0+u;
    float y[20];
    const float4* lp = (const float4*)(logits + r*20);
    #pragma unroll
    for (int q=0;q<5;q++){ float4 f=lp[q]; y[q*4]=f.x; y[q*4+1]=f.y; y[q*4+2]=f.z; y[q*4+3]=f.w; }
    #pragma unroll
    for (int c=0;c<20;c++) y[c]=y[c]-adjS[c];
    float m=-INFINITY;
    #pragma unroll
    for (int c=0;c<20;c++) m=fmaxf(m,y[c]);
    float s=0.f;
    #pragma unroll
    for (int c=0;c<20;c++){ y[c]=expf(y[c]-m); s+=y[c]; }
    #pragma unroll
    for (int c=0;c<20;c++) acc[c] += (double)(y[c]/s);
  }
  reduce20(acc, wred, csGs, tid, lane, wv);
  if (tid<20){ float c=csGs[tid]; float p=0.f;
    if (c > 20.0f) p = -logf(c/20.0f + 1e-8f);
    if (c > 0.0f && c < 3.0f) p = -0.5f*logf(c/3.0f + 1e-8f);
    pen[tid]=p; }
  __syncthreads();
  if (tid==0){ int f=0; for (int c=0;c<20;c++) if (pen[c]!=0.f) f=1; flagS=f; }
  __syncthreads();
  const int flag = flagS;

  // ---- pass 3: S0 rows -> (if pen) S1 rows; write Ucm, init G,R ----
  float G6[6], R6[6];
  for (int u=0;u<6;u++){
    const int r = r0+u;
    float y[20];
    const float4* lp = (const float4*)(logits + r*20);
    #pragma unroll
    for (int q=0;q<5;q++){ float4 f=lp[q]; y[q*4]=f.x; y[q*4+1]=f.y; y[q*4+2]=f.z; y[q*4+3]=f.w; }
    #pragma unroll
    for (int c=0;c<20;c++) y[c]=y[c]-adjS[c];
    float m=-INFINITY;
    #pragma unroll
    for (int c=0;c<20;c++) m=fmaxf(m,y[c]);
    float s=0.f;
    #pragma unroll
    for (int c=0;c<20;c++){ y[c]=expf(y[c]-m); s+=y[c]; }
    #pragma unroll
    for (int c=0;c<20;c++) y[c]=y[c]/s;         // y = S0 row
    float ts=0.f;
    if (flag){
      float m2=-INFINITY;
      #pragma unroll
      for (int c=0;c<20;c++){ y[c]=logf(y[c]+1e-8f)+pen[c]; m2=fmaxf(m2,y[c]); }
      float s2=0.f;
      #pragma unroll
      for (int c=0;c<20;c++){ y[c]=expf(y[c]-m2); s2+=y[c]; }
      #pragma unroll
      for (int c=0;c<20;c++){ float vv=y[c]/s2; Ucm[c*6144+r]=vv; ts+=vv; }
    } else {
      #pragma unroll
      for (int c=0;c<20;c++){ Ucm[c*6144+r]=y[c]; ts+=y[c]; }
    }
    G6[u]=1.0f; R6[u]=ts;
  }
  __syncthreads();

  // ---- constraints: sequential 20-column quantile/zero/renorm (scale form) ----
  if (flag){
    for (int k=0;k<20;k++){
      if (!(csGs[k] > 30.0f)) continue;   // very_over false -> column untouched
      float u6[6], sv6[6];
      #pragma unroll
      for (int u=0;u<6;u++){ u6[u]=Ucm[k*6144+r0+u]; sv6[u]=__fmul_rn(u6[u], G6[u]); }
      float vlo = selectKth6(sv6, 4300, hist, st, tid);
      float vhi;
      if (st[2] + 1u < st[3]) vhi = vlo;
      else {
        if (tid==0) st[4]=0xFFFFFFFFu;
        __syncthreads();
        unsigned kV = __float_as_uint(vlo);
        #pragma unroll
        for (int u=0;u<6;u++){ unsigned key=__float_as_uint(sv6[u]); if (key>kV) atomicMin(&st[4], key); }
        __syncthreads();
        vhi = __uint_as_float(st[4]);
      }
      // jnp.quantile(col,0.7): aq=f32(0.7)*6143 -> weights exact
      float thr = __fadd_rn(__fmul_rn(vlo, 0.89990234375f), __fmul_rn(vhi, 0.10009765625f));
      #pragma unroll
      for (int u=0;u<6;u++){
        if (sv6[u] < thr){
          Ucm[k*6144+r0+u] = 0.0f;
          float rs  = __fsub_rn(__fmul_rn(R6[u], G6[u]), sv6[u]);
          float rsm = fmaxf(rs, 1e-12f);
          G6[u] = __fdiv_rn(G6[u], rsm);
          R6[u] = __fsub_rn(R6[u], u6[u]);
        }
      }
      __syncthreads();
    }
  }

  // ---- hard rebalance: 5 x 20 sequential stable-rank column steps ----
  for (int it=0; it<5; it++){
    for (int c=0;c<20;c++){
      double d=0.0;
      #pragma unroll
      for (int u=0;u<6;u++) d += (double)__fmul_rn(Ucm[c*6144+r0+u], G6[u]);
      acc[c]=d;
    }
    reduce20(acc, wred, csS, tid, lane, wv);
    if (tid==0){ float s=0.f; for (int c=0;c<20;c++) s += fmaxf(20.0f-csS[c],0.f);
      wzeroS = (s==0.0f) ? 1 : 0; wsumS = s + 1e-8f; }
    __syncthreads();
    if (tid<20){
      float csf = csS[tid];
      actL[tid] = (csf > 20.0f) ? 1 : 0;
      int num = (int)ceilf(csf - 20.0f) + 5; if (num > 6144) num = 6144;
      numL[tid] = num;
      wLs[tid] = fmaxf(20.0f-csf,0.f) / wsumS;
    }
    __syncthreads();
    for (int k=0;k<20;k++){
      if (!actL[k]) continue;
      const int num = numL[k];
      float u6[6];
      #pragma unroll
      for (int u=0;u<6;u++) u6[u]=Ucm[k*6144+r0+u];
      int zc=0;
      #pragma unroll
      for (int u=0;u<6;u++) zc += (u6[u]==0.0f) ? 1 : 0;
      int zBase = blockExclScan(zc, tid, waveTot, waveBase, &totAllS);
      const int totZ = totAllS;
      if (num <= totZ && wzeroS){
        // fast path: w==0 exactly; weak = first `num` exact-zero rows by index.
        // Update is O(1) per row: set col k to 1e-8, fold renorm into G.
        int cnt = zBase;
        #pragma unroll
        for (int u=0;u<6;u++){
          if (u6[u]==0.0f){
            if (cnt < num){
              float Gold = G6[u];
              float t   = __fadd_rn(__fmul_rn(__fsub_rn(R6[u], u6[u]), Gold), 1e-8f);
              float rsm = fmaxf(t, 1e-12f);
              float un  = __fdiv_rn(1e-8f, Gold);
              Ucm[k*6144+r0+u] = un;
              G6[u] = __fdiv_rn(Gold, rsm);
              R6[u] = __fadd_rn(__fsub_rn(R6[u], u6[u]), un);
            }
            cnt++;
          }
        }
      } else {
        // general path (reference-faithful full-row update)
        float sv6[6];
        #pragma unroll
        for (int u=0;u<6;u++) sv6[u]=__fmul_rn(u6[u], G6[u]);
        bool wk[6];
        if (num <= totZ){
          int cnt = zBase;
          #pragma unroll
          for (int u=0;u<6;u++){ wk[u]=false; if (u6[u]==0.0f){ if (cnt<num) wk[u]=true; cnt++; } }
        } else {
          float V = selectKth6(sv6, num-1, hist, st, tid);
          unsigned kV = __float_as_uint(V);
          int L = (int)st[1];
          int Rq = num - L;
          int ec=0;
          #pragma unroll
          for (int u=0;u<6;u++) ec += (__float_as_uint(sv6[u])==kV) ? 1 : 0;
          int eBase = blockExclScan(ec, tid, waveTot, waveBase, &totAllS);
          int cnt = eBase;
          #pragma unroll
          for (int u=0;u<6;u++){
            unsigned key = __float_as_uint(sv6[u]); wk[u]=false;
            if (key < kV) wk[u]=true;
            else if (key == kV){ if (cnt < Rq) wk[u]=true; cnt++; }
          }
        }
        #pragma unroll
        for (int u=0;u<6;u++){
          if (wk[u]){
            const int r = r0+u;
            float rs=0.f;
            #pragma unroll
            for (int j=0;j<20;j++){
              float xv = (j==k) ? 1e-8f : __fmul_rn(Ucm[j*6144+r], G6[u]);
              xv = __fadd_rn(xv, __fmul_rn(wLs[j], 1e-8f));
              rs += fabsf(xv);
            }
            float rsm = fmaxf(rs, 1e-12f);
            float nR = 0.f;
            #pragma unroll
            for (int j=0;j<20;j++){
              float xv = (j==k) ? 1e-8f : __fmul_rn(Ucm[j*6144+r], G6[u]);
              xv = __fadd_rn(xv, __fmul_rn(wLs[j], 1e-8f));
              float nv = __fdiv_rn(xv, rsm);
              Ucm[j*6144+r] = nv; nR += nv;
            }
            G6[u]=1.0f; R6[u]=nR;
          }
        }
      }
      __syncthreads();
    }
  }

  // ---- materialize SW row-major ----
  for (int c=0;c<20;c++){
    #pragma unroll
    for (int u=0;u<6;u++) SW[(r0+u)*20+c] = __fmul_rn(Ucm[c*6144+r0+u], G6[u]);
  }
}

// ---------------- final pass: store S, entropy, cs_final, x_pooled ----------------
__global__ __launch_bounds__(256) void k_final(const float* __restrict__ SW, const float* __restrict__ xe,
    float* __restrict__ outXP, float* __restrict__ outS, float* __restrict__ csfin, double* __restrict__ entAcc){
  __shared__ float srow[8][20];
  __shared__ float csL[20];
  __shared__ double entL[4];
  const int tid = threadIdx.x;
  const int r0 = blockIdx.x * 256;
  const int lane = tid & 63, wvq = tid >> 6;
  if (tid < 20) csL[tid]=0.f;
  __syncthreads();
  {
    const int r = r0 + tid;
    float sv[20]; float ent=0.f;
    #pragma unroll
    for (int c=0;c<20;c++){ sv[c]=SW[r*20+c]; }
    #pragma unroll
    for (int c=0;c<20;c++){ outS[r*20+c]=sv[c]; ent += sv[c]*logf(sv[c]+1e-08f); }
    #pragma unroll
    for (int c=0;c<20;c++) atomicAdd(&csL[c], sv[c]);
    double ed = (double)ent;
    for (int off=32;off>0;off>>=1) ed += __shfl_down(ed, off);
    if (lane==0) entL[wvq]=ed;
  }
  __syncthreads();
  if (tid==0) atomicAdd(entAcc, entL[0]+entL[1]+entL[2]+entL[3]);
  if (tid<20) atomicAdd(&csfin[tid], csL[tid]);
  __syncthreads();
  float acc[20];
  #pragma unroll
  for (int c=0;c<20;c++) acc[c]=0.f;
  for (int base=0;base<256;base+=8){
    if (tid < 160){ int i=tid/20, c=tid%20; srow[i][c]=SW[(r0+base+i)*20+c]; }
    __syncthreads();
    for (int i=0;i<8;i++){
      float xv = xe[(r0+base+i)*256 + tid];
      #pragma unroll
      for (int c=0;c<20;c++) acc[c]=fmaf(srow[i][c], xv, acc[c]);
    }
    __syncthreads();
  }
  #pragma unroll
  for (int c=0;c<20;c++) atomicAdd(&outXP[c*256+tid], acc[c]);
}

// ---------------- edges: dedup bitmap, T = adj@S, edge loss term ----------------
__global__ __launch_bounds__(256) void k_edges(const int* __restrict__ ei, const float* __restrict__ SW,
    unsigned int* __restrict__ bitmap, float* __restrict__ T, double* __restrict__ edgeAcc){
  __shared__ double wsum[4];
  const int tid = threadIdx.x;
  const int e = blockIdx.x*256 + tid;
  const int lane = tid & 63, wvq = tid >> 6;
  const int i = ei[e], j = ei[NE+e];
  unsigned bit = (unsigned)i*6144u + (unsigned)j;
  unsigned w = bit >> 5, m = 1u << (bit & 31u);
  unsigned old = atomicOr(&bitmap[w], m);
  float contrib = 0.f;
  if (!(old & m)){
    float p = 0.f;
    #pragma unroll
    for (int c=0;c<20;c++) p = fmaf(SW[i*20+c], SW[j*20+c], p);
    #pragma unroll
    for (int c=0;c<20;c++) atomicAdd(&T[i*20+c], SW[j*20+c]);
    float pcl = fminf(fmaxf(p,0.f),1.f);
    float lg  = fmaxf(logf(pcl),   -100.f);
    float l1  = fmaxf(log1pf(-pcl),-100.f);
    contrib = lg - l1;
  }
  double cd = (double)contrib;
  for (int off=32;off>0;off>>=1) cd += __shfl_down(cd, off);
  if (lane==0) wsum[wvq]=cd;
  __syncthreads();
  if (tid==0) atomicAdd(edgeAcc, wsum[0]+wsum[1]+wsum[2]+wsum[3]);
}

// ---------------- adj_pooled = S.T @ T ----------------
__global__ __launch_bounds__(400) void k_adjpool(const float* __restrict__ SW, const float* __restrict__ T,
    float* __restrict__ outAdj){
  const int tid = threadIdx.x;          // 0..399
  const int c = tid/20, d = tid%20;
  const int r0 = blockIdx.x*256;
  float acc=0.f;
  for (int i=0;i<256;i++) acc = fmaf(SW[(r0+i)*20+c], T[(r0+i)*20+d], acc);
  atomicAdd(&outAdj[c*20+d], acc);
}

// ---------------- all-pair sum of clamped log1p(-p) ----------------
__global__ __launch_bounds__(256) void k_link(const float* __restrict__ SW, double* __restrict__ acc){
  __shared__ float Si[256][21];
  __shared__ float Sj[256][21];
  __shared__ double wsum[4];
  const int tid = threadIdx.x;
  const int ib = blockIdx.x*256, jb = blockIdx.y*256;
  const int lane = tid & 63, wvq = tid >> 6;
  for (int idx=tid; idx<5120; idx+=256){ int r=idx/20, c=idx%20; Si[r][c]=SW[(ib+r)*20+c]; }
  for (int idx=tid; idx<5120; idx+=256){ int r=idx/20, c=idx%20; Sj[r][c]=SW[(jb+r)*20+c]; }
  __syncthreads();
  float rA[20];
  #pragma unroll
  for (int c=0;c<20;c++) rA[c]=Si[tid][c];
  float af = 0.f;
  for (int jj=0;jj<256;jj++){
    float p=0.f;
    #pragma unroll
    for (int c=0;c<20;c++) p = fmaf(rA[c], Sj[jj][c], p);
    float pcl = fminf(fmaxf(p,0.f),1.f);
    af += fmaxf(log1pf(-pcl), -100.f);
  }
  double cd = (double)af;
  for (int off=32;off>0;off>>=1) cd += __shfl_down(cd, off);
  if (lane==0) wsum[wvq]=cd;
  __syncthreads();
  if (tid==0) atomicAdd(acc, wsum[0]+wsum[1]+wsum[2]+wsum[3]);
}

// ---------------- aux scalar ----------------
__global__ void k_aux(const double* __restrict__ dAcc, const float* __restrict__ csfin, float* __restrict__ outAux){
  const double nsq = 6144.0*6144.0;
  float link = (float)(-(dAcc[0]+dAcc[1])/nsq);
  float ent  = (float)(-(dAcc[2]/6144.0));
  float s=0.f;
  for (int c=0;c<20;c++) s += fabsf(csfin[c]-307.2f);
  float bal = (s/20.0f)/307.2f;
  outAux[0] = link + 0.1f*ent + 0.5f*bal;
}

extern "C" void kernel_launch(void* const* d_in, const int* in_sizes, int n_in,
                              void* d_out, int out_size, void* d_ws, size_t ws_size,
                              hipStream_t stream) {
  const float* x   = (const float*)d_in[0];
  const int*   ei  = (const int*)d_in[1];
  // d_in[2] = lv_group_ids: dead (LV table is never 0 -> mask is identity)
  const float* W1  = (const float*)d_in[3];
  const float* b1  = (const float*)d_in[4];
  const float* W2  = (const float*)d_in[5];
  const float* b2  = (const float*)d_in[6];
  const float* W3  = (const float*)d_in[7];
  const float* b3  = (const float*)d_in[8];
  const float* We1 = (const float*)d_in[9];
  const float* be1 = (const float*)d_in[10];
  const float* We2 = (const float*)d_in[11];
  const float* be2 = (const float*)d_in[12];

  char* ws = (char*)d_ws;
  float* T        = (float*)(ws + OFF_T);
  unsigned int* bitmap = (unsigned int*)(ws + OFF_BITMAP);
  float* csfin    = (float*)(ws + OFF_CSFIN);
  double* dAcc    = (double*)(ws + OFF_DACC);
  float* logits   = (float*)(ws + OFF_LOGITS);
  float* Ucm      = (float*)(ws + OFF_UCM);
  float* SW       = (float*)(ws + OFF_SW);
  float* xe       = (float*)(ws + OFF_XE);

  float* out   = (float*)d_out;
  float* outXP = out;            // 20*256
  float* outAdj= out + 5120;     // 20*20
  float* outS  = out + 5520;     // 6144*20
  float* outAux= out + 128400;   // 1

  hipMemsetAsync(d_ws, 0, (size_t)ZERO_BYTES, stream);
  hipMemsetAsync(d_out, 0, (size_t)out_size*sizeof(float), stream);

  k_mlp<<<384, 128, 0, stream>>>(x, W1,b1, W2,b2, W3,b3, logits);
  k_embed<<<384, 256, 0, stream>>>(x, We1,be1, We2,be2, xe);
  k_mid<<<1, 1024, 0, stream>>>(logits, Ucm, SW);
  k_final<<<24, 256, 0, stream>>>(SW, xe, outXP, outS, csfin, &dAcc[2]);
  k_edges<<<384, 256, 0, stream>>>(ei, SW, bitmap, T, &dAcc[1]);
  k_adjpool<<<24, 400, 0, stream>>>(SW, T, outAdj);
  k_link<<<dim3(24,24), 256, 0, stream>>>(SW, &dAcc[0]);
  k_aux<<<1, 1, 0, stream>>>(dAcc, csfin, outAux);
}

// Round 3
// 1628.253 us; speedup vs baseline: 1.4163x; 1.2024x over previous
//
#include <hip/hip_runtime.h>
#include <math.h>

#define N_NODES 6144
#define KCL 20
#define NE 98304

// ---------------- workspace layout (bytes) ----------------
#define OFF_T        0ull          // 122880 f32 (zeroed)
#define OFF_BITMAP   491520ull     // 4718592 B bitmap (zeroed)
#define OFF_CSFIN    5210272ull    // 20 f32 (zeroed)
#define OFF_DACC     5210368ull    // 4 doubles (zeroed): [0]=all-pair log1mp, [1]=edge term, [2]=entropy
#define ZERO_BYTES   5210400ull
#define OFF_LOGITS   5210624ull
#define OFF_SW       6685184ull    // 6144*20 f32 row-major
#define OFF_XE       7176704ull    // 6144*256 f32

// ---------------- MLP: logits = (relu(relu(x@W1+b1)@W2+b2))@W3+b3 ----------------
__global__ __launch_bounds__(128) void k_mlp(const float* __restrict__ x,
    const float* __restrict__ W1, const float* __restrict__ b1,
    const float* __restrict__ W2, const float* __restrict__ b2,
    const float* __restrict__ W3, const float* __restrict__ b3,
    float* __restrict__ logits){
  __shared__ float xs[16][256];
  __shared__ float h1[16][128];
  __shared__ float h2[16][64];
  const int tid = threadIdx.x;
  const int r0 = blockIdx.x * 16;
  for (int idx = tid; idx < 16*256; idx += 128){ int u = idx >> 8, i = idx & 255; xs[u][i] = x[(r0+u)*256 + i]; }
  __syncthreads();
  {
    float acc[16]; float bb = b1[tid];
    #pragma unroll
    for (int u=0;u<16;u++) acc[u]=bb;
    for (int i=0;i<256;i++){ float wv = W1[i*128+tid];
      #pragma unroll
      for (int u=0;u<16;u++) acc[u]=fmaf(xs[u][i], wv, acc[u]); }
    #pragma unroll
    for (int u=0;u<16;u++) h1[u][tid]=fmaxf(acc[u],0.f);
  }
  __syncthreads();
  if (tid < 64){
    float acc[16]; float bb = b2[tid];
    #pragma unroll
    for (int u=0;u<16;u++) acc[u]=bb;
    for (int i=0;i<128;i++){ float wv = W2[i*64+tid];
      #pragma unroll
      for (int u=0;u<16;u++) acc[u]=fmaf(h1[u][i], wv, acc[u]); }
    #pragma unroll
    for (int u=0;u<16;u++) h2[u][tid]=fmaxf(acc[u],0.f);
  }
  __syncthreads();
  if (tid < 20){
    float acc[16]; float bb = b3[tid];
    #pragma unroll
    for (int u=0;u<16;u++) acc[u]=bb;
    for (int i=0;i<64;i++){ float wv = W3[i*20+tid];
      #pragma unroll
      for (int u=0;u<16;u++) acc[u]=fmaf(h2[u][i], wv, acc[u]); }
    #pragma unroll
    for (int u=0;u<16;u++) logits[(r0+u)*20+tid]=acc[u];
  }
}

// ---------------- embed MLP: xe = relu(x@We1+be1)@We2+be2 ----------------
__global__ __launch_bounds__(256) void k_embed(const float* __restrict__ x,
    const float* __restrict__ We1, const float* __restrict__ be1,
    const float* __restrict__ We2, const float* __restrict__ be2,
    float* __restrict__ xe){
  __shared__ float xs[16][256];
  __shared__ float h[16][256];
  const int tid = threadIdx.x;
  const int r0 = blockIdx.x * 16;
  for (int u=0;u<16;u++) xs[u][tid] = x[(r0+u)*256 + tid];
  __syncthreads();
  float acc[16];
  { float bb = be1[tid];
    #pragma unroll
    for (int u=0;u<16;u++) acc[u]=bb; }
  for (int i=0;i<256;i++){ float wv = We1[i*256+tid];
    #pragma unroll
    for (int u=0;u<16;u++) acc[u]=fmaf(xs[u][i], wv, acc[u]); }
  #pragma unroll
  for (int u=0;u<16;u++) h[u][tid]=fmaxf(acc[u],0.f);
  __syncthreads();
  { float bb = be2[tid];
    #pragma unroll
    for (int u=0;u<16;u++) acc[u]=bb; }
  for (int i=0;i<256;i++){ float wv = We2[i*256+tid];
    #pragma unroll
    for (int u=0;u<16;u++) acc[u]=fmaf(h[u][i], wv, acc[u]); }
  #pragma unroll
  for (int u=0;u<16;u++) xe[(r0+u)*256+tid]=acc[u];
}

// ---------------- helpers for the fused middle kernel ----------------
__device__ __forceinline__ void reduce20(const double* acc, double* wred, float* out,
                                         int tid, int lane, int wv){
  #pragma unroll
  for (int c=0;c<20;c++){
    double d = acc[c];
    for (int off=32;off>0;off>>=1) d += __shfl_down(d, off);
    if (lane==0) wred[wv*20+c]=d;
  }
  __syncthreads();
  if (tid<20){ double s=0.0; for (int w2=0;w2<16;w2++) s += wred[w2*20+tid]; out[tid]=(float)s; }
  __syncthreads();
}

__device__ __forceinline__ int blockExclScan(int val, int tid, int* waveTot, int* waveBase, int* totAll){
  __syncthreads();   // protect reuse of waveTot/totAll across back-to-back calls
  const int lane = tid & 63, wv = tid >> 6;
  int inc = val;
  for (int off=1;off<64;off<<=1){ int nv=__shfl_up(inc,off); if (lane>=off) inc+=nv; }
  if (lane==63) waveTot[wv]=inc;
  __syncthreads();
  if (tid==0){ int run=0; for (int w2=0;w2<16;w2++){ waveBase[w2]=run; run+=waveTot[w2]; } *totAll=run; }
  __syncthreads();
  return waveBase[wv] + inc - val;
}

// block radix select (k-th smallest, non-negative f32), 4-replica histogram
// st[0]=prefix bits, st[1]=count strictly below value, st[2]=rank within equal group, st[3]=count at value
__device__ __forceinline__ float selectKth6(const float v6[6], int rank0, unsigned int (*hist)[2048],
                            unsigned int* st, int tid){
  const int rep = (tid>>6)&3;
  if (tid==0){ st[0]=0u; st[1]=0u; st[2]=(unsigned)rank0; st[3]=0u; }
  __syncthreads();
  for (int p=0;p<3;p++){
    const int shift = (p==0)?21:((p==1)?10:0);
    const int bins  = (p==2)?1024:2048;
    for (int b=tid;b<bins;b+=1024){ hist[0][b]=0u; hist[1][b]=0u; hist[2][b]=0u; hist[3][b]=0u; }
    __syncthreads();
    const unsigned pref = st[0];
    #pragma unroll
    for (int u=0;u<6;u++){
      unsigned key = __float_as_uint(v6[u]);
      bool ok;
      if (p==0) ok = true;
      else { int us = (p==1)?21:10; ok = ((key>>us)==(pref>>us)); }
      if (ok) atomicAdd(&hist[rep][(key>>shift)&(bins-1)], 1u);
    }
    __syncthreads();
    if (tid < 64){
      const int per = bins >> 6;
      const int rank = (int)st[2];
      int cnt = 0;
      for (int b=0;b<per;b++){ int i=tid*per+b; cnt += (int)(hist[0][i]+hist[1][i]+hist[2][i]+hist[3][i]); }
      int cum = cnt;
      for (int off=1;off<64;off<<=1){ int nv=__shfl_up(cum,off); if (tid>=off) cum+=nv; }
      unsigned long long bal = __ballot(cum > rank);
      int ldr = (int)__ffsll(bal) - 1;
      int base = __shfl(cum-cnt, ldr);
      if (tid == ldr){
        int run = base; int bsel = -1; unsigned hc = 0u;
        for (int b=0;b<per;b++){ int i=ldr*per+b;
          unsigned h = hist[0][i]+hist[1][i]+hist[2][i]+hist[3][i];
          if (run+(int)h > rank){ bsel=i; hc=h; break; } run+=(int)h; }
        st[0] = st[0] | (((unsigned)bsel) << shift);
        st[1] = st[1] + (unsigned)run;
        st[2] = (unsigned)(rank - run);
        st[3] = hc;
      }
    }
    __syncthreads();
  }
  return __uint_as_float(st[0]);
}

// ---------------- fused middle: register-resident S ----------------
// Each thread owns rows r = tid*6+u in S[6][20] (VGPRs). Per-row scale G6 and
// unscaled row-sum R6 make renormalization O(1). All loops over columns are
// fully unrolled so S never leaves the register file until the final SW write.
__global__ __launch_bounds__(1024) void k_mid(const float* __restrict__ logits,
    float* __restrict__ SW){
  __shared__ unsigned int hist[4][2048];
  __shared__ unsigned int st[8];
  __shared__ int waveTot[16]; __shared__ int waveBase[16]; __shared__ int totAllS;
  __shared__ double wred[320];
  __shared__ float cs0s[20], csGs[20], adjS[20], pen[20], csS[20], wLs[20];
  __shared__ int numL[20], actL[20];
  __shared__ float wsumS; __shared__ int wzeroS; __shared__ int flagS;
  const int tid = threadIdx.x;
  const int lane = tid & 63, wv = tid >> 6;
  const int r0 = tid*6;

  float S[6][20];
  float G6[6], R6[6];
  // ---- load logits rows into registers ----
  #pragma unroll
  for (int u=0;u<6;u++){
    const float4* lp = (const float4*)(logits + (r0+u)*20);
    #pragma unroll
    for (int q=0;q<5;q++){ float4 f=lp[q]; S[u][q*4]=f.x; S[u][q*4+1]=f.y; S[u][q*4+2]=f.z; S[u][q*4+3]=f.w; }
  }

  double acc[20];
  // ---- pass 1: colsum0 = softmax(logits).sum(0) ----
  #pragma unroll
  for (int c=0;c<20;c++) acc[c]=0.0;
  #pragma unroll
  for (int u=0;u<6;u++){
    float y[20]; float m=-INFINITY;
    #pragma unroll
    for (int c=0;c<20;c++){ y[c]=S[u][c]; m=fmaxf(m,y[c]); }
    float s=0.f;
    #pragma unroll
    for (int c=0;c<20;c++){ y[c]=expf(y[c]-m); s+=y[c]; }
    #pragma unroll
    for (int c=0;c<20;c++) acc[c] += (double)(y[c]/s);
  }
  reduce20(acc, wred, cs0s, tid, lane, wv);
  if (tid<20) adjS[tid] = (0.1f*(cs0s[tid]-307.2f))/307.2f;
  __syncthreads();

  // ---- pass 2: S0 = softmax(logits-adj); S := S0; csG = S0.sum(0) ----
  #pragma unroll
  for (int c=0;c<20;c++) acc[c]=0.0;
  #pragma unroll
  for (int u=0;u<6;u++){
    float y[20]; float m=-INFINITY;
    #pragma unroll
    for (int c=0;c<20;c++){ y[c]=S[u][c]-adjS[c]; m=fmaxf(m,y[c]); }
    float s=0.f;
    #pragma unroll
    for (int c=0;c<20;c++){ y[c]=expf(y[c]-m); s+=y[c]; }
    #pragma unroll
    for (int c=0;c<20;c++){ float v=y[c]/s; S[u][c]=v; acc[c]+=(double)v; }
  }
  reduce20(acc, wred, csGs, tid, lane, wv);
  if (tid<20){ float c=csGs[tid]; float p=0.f;
    if (c > 20.0f) p = -logf(c/20.0f + 1e-8f);
    if (c > 0.0f && c < 3.0f) p = -0.5f*logf(c/3.0f + 1e-8f);
    pen[tid]=p; }
  __syncthreads();
  if (tid==0){ int f=0; for (int c=0;c<20;c++) if (pen[c]!=0.f) f=1; flagS=f; }
  __syncthreads();
  const int flag = flagS;

  // ---- pass 3: if pen: S := softmax(log(S0+1e-8)+pen); init G,R ----
  #pragma unroll
  for (int u=0;u<6;u++){
    float ts=0.f;
    if (flag){
      float y[20]; float m2=-INFINITY;
      #pragma unroll
      for (int c=0;c<20;c++){ y[c]=logf(S[u][c]+1e-8f)+pen[c]; m2=fmaxf(m2,y[c]); }
      float s2=0.f;
      #pragma unroll
      for (int c=0;c<20;c++){ y[c]=expf(y[c]-m2); s2+=y[c]; }
      #pragma unroll
      for (int c=0;c<20;c++){ float vv=y[c]/s2; S[u][c]=vv; ts+=vv; }
    } else {
      #pragma unroll
      for (int c=0;c<20;c++) ts+=S[u][c];
    }
    G6[u]=1.0f; R6[u]=ts;
  }
  __syncthreads();

  // ---- constraints: sequential 20-column quantile/zero/renorm (scale form) ----
  if (flag){
    #pragma unroll
    for (int k=0;k<20;k++){
      if (csGs[k] > 30.0f){   // uniform branch
        float u6[6], sv6[6];
        #pragma unroll
        for (int u=0;u<6;u++){ u6[u]=S[u][k]; sv6[u]=__fmul_rn(u6[u], G6[u]); }
        float vlo = selectKth6(sv6, 4300, hist, st, tid);
        float vhi;
        if (st[2] + 1u < st[3]) vhi = vlo;
        else {
          if (tid==0) st[4]=0xFFFFFFFFu;
          __syncthreads();
          unsigned kV = __float_as_uint(vlo);
          #pragma unroll
          for (int u=0;u<6;u++){ unsigned key=__float_as_uint(sv6[u]); if (key>kV) atomicMin(&st[4], key); }
          __syncthreads();
          vhi = __uint_as_float(st[4]);
        }
        // jnp.quantile(col,0.7): aq=f32(0.7)*6143 -> weights exact
        float thr = __fadd_rn(__fmul_rn(vlo, 0.89990234375f), __fmul_rn(vhi, 0.10009765625f));
        #pragma unroll
        for (int u=0;u<6;u++){
          if (sv6[u] < thr){
            S[u][k] = 0.0f;
            float rs  = __fsub_rn(__fmul_rn(R6[u], G6[u]), sv6[u]);
            float rsm = fmaxf(rs, 1e-12f);
            G6[u] = __fdiv_rn(G6[u], rsm);
            R6[u] = __fsub_rn(R6[u], u6[u]);
          }
        }
        __syncthreads();
      }
    }
  }

  // ---- hard rebalance: 5 x 20 sequential stable-rank column steps ----
  for (int it=0; it<5; it++){
    #pragma unroll
    for (int c=0;c<20;c++){
      double d=0.0;
      #pragma unroll
      for (int u=0;u<6;u++) d += (double)__fmul_rn(S[u][c], G6[u]);
      acc[c]=d;
    }
    reduce20(acc, wred, csS, tid, lane, wv);
    if (tid==0){ float s=0.f; for (int c=0;c<20;c++) s += fmaxf(20.0f-csS[c],0.f);
      wzeroS = (s==0.0f) ? 1 : 0; wsumS = s + 1e-8f; }
    __syncthreads();
    if (tid<20){
      float csf = csS[tid];
      actL[tid] = (csf > 20.0f) ? 1 : 0;
      int num = (int)ceilf(csf - 20.0f) + 5; if (num > 6144) num = 6144;
      numL[tid] = num;
      wLs[tid] = fmaxf(20.0f-csf,0.f) / wsumS;
    }
    __syncthreads();
    #pragma unroll
    for (int k=0;k<20;k++){
      if (actL[k]){   // uniform branch
        const int num = numL[k];
        float u6[6];
        #pragma unroll
        for (int u=0;u<6;u++) u6[u]=S[u][k];
        int zc=0;
        #pragma unroll
        for (int u=0;u<6;u++) zc += (u6[u]==0.0f) ? 1 : 0;
        int zBase = blockExclScan(zc, tid, waveTot, waveBase, &totAllS);
        const int totZ = totAllS;
        if (num <= totZ && wzeroS){
          // fast path: w==0 exactly; weak = first `num` exact-zero rows by index.
          int cnt = zBase;
          #pragma unroll
          for (int u=0;u<6;u++){
            if (u6[u]==0.0f){
              if (cnt < num){
                float Gold = G6[u];
                float t   = __fadd_rn(__fmul_rn(__fsub_rn(R6[u], u6[u]), Gold), 1e-8f);
                float rsm = fmaxf(t, 1e-12f);
                float un  = __fdiv_rn(1e-8f, Gold);
                S[u][k] = un;
                G6[u] = __fdiv_rn(Gold, rsm);
                R6[u] = __fadd_rn(__fsub_rn(R6[u], u6[u]), un);
              }
              cnt++;
            }
          }
        } else {
          // general path (reference-faithful full-row update)
          float sv6[6];
          #pragma unroll
          for (int u=0;u<6;u++) sv6[u]=__fmul_rn(u6[u], G6[u]);
          bool wk[6];
          if (num <= totZ){
            int cnt = zBase;
            #pragma unroll
            for (int u=0;u<6;u++){ wk[u]=false; if (u6[u]==0.0f){ if (cnt<num) wk[u]=true; cnt++; } }
          } else {
            float V = selectKth6(sv6, num-1, hist, st, tid);
            unsigned kV = __float_as_uint(V);
            int L = (int)st[1];
            int Rq = num - L;
            int ec=0;
            #pragma unroll
            for (int u=0;u<6;u++) ec += (__float_as_uint(sv6[u])==kV) ? 1 : 0;
            int eBase = blockExclScan(ec, tid, waveTot, waveBase, &totAllS);
            int cnt = eBase;
            #pragma unroll
            for (int u=0;u<6;u++){
              unsigned key = __float_as_uint(sv6[u]); wk[u]=false;
              if (key < kV) wk[u]=true;
              else if (key == kV){ if (cnt < Rq) wk[u]=true; cnt++; }
            }
          }
          #pragma unroll
          for (int u=0;u<6;u++){
            if (wk[u]){
              float rs=0.f; float xv2[20];
              #pragma unroll
              for (int j=0;j<20;j++){
                float xv = (j==k) ? 1e-8f : __fmul_rn(S[u][j], G6[u]);
                xv = __fadd_rn(xv, __fmul_rn(wLs[j], 1e-8f));
                xv2[j]=xv; rs += fabsf(xv);
              }
              float rsm = fmaxf(rs, 1e-12f);
              float nR = 0.f;
              #pragma unroll
              for (int j=0;j<20;j++){
                float nv = __fdiv_rn(xv2[j], rsm);
                S[u][j] = nv; nR += nv;
              }
              G6[u]=1.0f; R6[u]=nR;
            }
          }
        }
        __syncthreads();
      }
    }
  }

  // ---- materialize SW row-major ----
  #pragma unroll
  for (int u=0;u<6;u++){
    #pragma unroll
    for (int c=0;c<20;c++) SW[(r0+u)*20+c] = __fmul_rn(S[u][c], G6[u]);
  }
}

// ---------------- final pass: store S, entropy, cs_final, x_pooled ----------------
__global__ __launch_bounds__(256) void k_final(const float* __restrict__ SW, const float* __restrict__ xe,
    float* __restrict__ outXP, float* __restrict__ outS, float* __restrict__ csfin, double* __restrict__ entAcc){
  __shared__ float srow[8][20];
  __shared__ float csL[20];
  __shared__ double entL[4];
  const int tid = threadIdx.x;
  const int r0 = blockIdx.x * 256;
  const int lane = tid & 63, wvq = tid >> 6;
  if (tid < 20) csL[tid]=0.f;
  __syncthreads();
  {
    const int r = r0 + tid;
    float sv[20]; float ent=0.f;
    #pragma unroll
    for (int c=0;c<20;c++){ sv[c]=SW[r*20+c]; }
    #pragma unroll
    for (int c=0;c<20;c++){ outS[r*20+c]=sv[c]; ent += sv[c]*logf(sv[c]+1e-08f); }
    #pragma unroll
    for (int c=0;c<20;c++) atomicAdd(&csL[c], sv[c]);
    double ed = (double)ent;
    for (int off=32;off>0;off>>=1) ed += __shfl_down(ed, off);
    if (lane==0) entL[wvq]=ed;
  }
  __syncthreads();
  if (tid==0) atomicAdd(entAcc, entL[0]+entL[1]+entL[2]+entL[3]);
  if (tid<20) atomicAdd(&csfin[tid], csL[tid]);
  __syncthreads();
  float acc[20];
  #pragma unroll
  for (int c=0;c<20;c++) acc[c]=0.f;
  for (int base=0;base<256;base+=8){
    if (tid < 160){ int i=tid/20, c=tid%20; srow[i][c]=SW[(r0+base+i)*20+c]; }
    __syncthreads();
    for (int i=0;i<8;i++){
      float xv = xe[(r0+base+i)*256 + tid];
      #pragma unroll
      for (int c=0;c<20;c++) acc[c]=fmaf(srow[i][c], xv, acc[c]);
    }
    __syncthreads();
  }
  #pragma unroll
  for (int c=0;c<20;c++) atomicAdd(&outXP[c*256+tid], acc[c]);
}

// ---------------- edges: dedup bitmap, T = adj@S, edge loss term ----------------
__global__ __launch_bounds__(256) void k_edges(const int* __restrict__ ei, const float* __restrict__ SW,
    unsigned int* __restrict__ bitmap, float* __restrict__ T, double* __restrict__ edgeAcc){
  __shared__ double wsum[4];
  const int tid = threadIdx.x;
  const int e = blockIdx.x*256 + tid;
  const int lane = tid & 63, wvq = tid >> 6;
  const int i = ei[e], j = ei[NE+e];
  unsigned bit = (unsigned)i*6144u + (unsigned)j;
  unsigned w = bit >> 5, m = 1u << (bit & 31u);
  unsigned old = atomicOr(&bitmap[w], m);
  float contrib = 0.f;
  if (!(old & m)){
    float p = 0.f;
    #pragma unroll
    for (int c=0;c<20;c++) p = fmaf(SW[i*20+c], SW[j*20+c], p);
    #pragma unroll
    for (int c=0;c<20;c++) atomicAdd(&T[i*20+c], SW[j*20+c]);
    float pcl = fminf(fmaxf(p,0.f),1.f);
    float lg  = fmaxf(logf(pcl),   -100.f);
    float l1  = fmaxf(log1pf(-pcl),-100.f);
    contrib = lg - l1;
  }
  double cd = (double)contrib;
  for (int off=32;off>0;off>>=1) cd += __shfl_down(cd, off);
  if (lane==0) wsum[wvq]=cd;
  __syncthreads();
  if (tid==0) atomicAdd(edgeAcc, wsum[0]+wsum[1]+wsum[2]+wsum[3]);
}

// ---------------- adj_pooled = S.T @ T ----------------
__global__ __launch_bounds__(400) void k_adjpool(const float* __restrict__ SW, const float* __restrict__ T,
    float* __restrict__ outAdj){
  const int tid = threadIdx.x;          // 0..399
  const int c = tid/20, d = tid%20;
  const int r0 = blockIdx.x*256;
  float acc=0.f;
  for (int i=0;i<256;i++) acc = fmaf(SW[(r0+i)*20+c], T[(r0+i)*20+d], acc);
  atomicAdd(&outAdj[c*20+d], acc);
}

// ---------------- all-pair sum of clamped log1p(-p) ----------------
__global__ __launch_bounds__(256) void k_link(const float* __restrict__ SW, double* __restrict__ acc){
  __shared__ float Si[256][21];
  __shared__ float Sj[256][21];
  __shared__ double wsum[4];
  const int tid = threadIdx.x;
  const int ib = blockIdx.x*256, jb = blockIdx.y*256;
  const int lane = tid & 63, wvq = tid >> 6;
  for (int idx=tid; idx<5120; idx+=256){ int r=idx/20, c=idx%20; Si[r][c]=SW[(ib+r)*20+c]; }
  for (int idx=tid; idx<5120; idx+=256){ int r=idx/20, c=idx%20; Sj[r][c]=SW[(jb+r)*20+c]; }
  __syncthreads();
  float rA[20];
  #pragma unroll
  for (int c=0;c<20;c++) rA[c]=Si[tid][c];
  float af = 0.f;
  for (int jj=0;jj<256;jj++){
    float p=0.f;
    #pragma unroll
    for (int c=0;c<20;c++) p = fmaf(rA[c], Sj[jj][c], p);
    float pcl = fminf(fmaxf(p,0.f),1.f);
    af += fmaxf(log1pf(-pcl), -100.f);
  }
  double cd = (double)af;
  for (int off=32;off>0;off>>=1) cd += __shfl_down(cd, off);
  if (lane==0) wsum[wvq]=cd;
  __syncthreads();
  if (tid==0) atomicAdd(acc, wsum[0]+wsum[1]+wsum[2]+wsum[3]);
}

// ---------------- aux scalar ----------------
__global__ void k_aux(const double* __restrict__ dAcc, const float* __restrict__ csfin, float* __restrict__ outAux){
  const double nsq = 6144.0*6144.0;
  float link = (float)(-(dAcc[0]+dAcc[1])/nsq);
  float ent  = (float)(-(dAcc[2]/6144.0));
  float s=0.f;
  for (int c=0;c<20;c++) s += fabsf(csfin[c]-307.2f);
  float bal = (s/20.0f)/307.2f;
  outAux[0] = link + 0.1f*ent + 0.5f*bal;
}

extern "C" void kernel_launch(void* const* d_in, const int* in_sizes, int n_in,
                              void* d_out, int out_size, void* d_ws, size_t ws_size,
                              hipStream_t stream) {
  const float* x   = (const float*)d_in[0];
  const int*   ei  = (const int*)d_in[1];
  // d_in[2] = lv_group_ids: dead (LV table is never 0 -> mask is identity)
  const float* W1  = (const float*)d_in[3];
  const float* b1  = (const float*)d_in[4];
  const float* W2  = (const float*)d_in[5];
  const float* b2  = (const float*)d_in[6];
  const float* W3  = (const float*)d_in[7];
  const float* b3  = (const float*)d_in[8];
  const float* We1 = (const float*)d_in[9];
  const float* be1 = (const float*)d_in[10];
  const float* We2 = (const float*)d_in[11];
  const float* be2 = (const float*)d_in[12];

  char* ws = (char*)d_ws;
  float* T        = (float*)(ws + OFF_T);
  unsigned int* bitmap = (unsigned int*)(ws + OFF_BITMAP);
  float* csfin    = (float*)(ws + OFF_CSFIN);
  double* dAcc    = (double*)(ws + OFF_DACC);
  float* logits   = (float*)(ws + OFF_LOGITS);
  float* SW       = (float*)(ws + OFF_SW);
  float* xe       = (float*)(ws + OFF_XE);

  float* out   = (float*)d_out;
  float* outXP = out;            // 20*256
  float* outAdj= out + 5120;     // 20*20
  float* outS  = out + 5520;     // 6144*20
  float* outAux= out + 128400;   // 1

  hipMemsetAsync(d_ws, 0, (size_t)ZERO_BYTES, stream);
  hipMemsetAsync(d_out, 0, (size_t)out_size*sizeof(float), stream);

  k_mlp<<<384, 128, 0, stream>>>(x, W1,b1, W2,b2, W3,b3, logits);
  k_embed<<<384, 256, 0, stream>>>(x, We1,be1, We2,be2, xe);
  k_mid<<<1, 1024, 0, stream>>>(logits, SW);
  k_final<<<24, 256, 0, stream>>>(SW, xe, outXP, outS, csfin, &dAcc[2]);
  k_edges<<<384, 256, 0, stream>>>(ei, SW, bitmap, T, &dAcc[1]);
  k_adjpool<<<24, 400, 0, stream>>>(SW, T, outAdj);
  k_link<<<dim3(24,24), 256, 0, stream>>>(SW, &dAcc[0]);
  k_aux<<<1, 1, 0, stream>>>(dAcc, csfin, outAux);
}